// Round 3
// baseline (197.144 us; speedup 1.0000x reference)
//
#include <hip/hip_runtime.h>
#include <hip/hip_cooperative_groups.h>
#include <math.h>

namespace cg = cooperative_groups;

// YOLOv3 loss on MI355X — single cooperative dispatch.
// Layouts: pred (B, A, 85) f32 [0..4 reg, 5..84 cls probs]; ann (B, M, 5) f32
// [x_tl, y_tl, w, h, cls(-1=pad)]; anchors (A, 4) f32 [cx, cy, w, h].
// d_ws: per-block partials [B][P][3] = {cls_sum, reg_sq_sum, npos}, written
// unconditionally (no zero-init needed). grid.sync() then block (0,0)
// reduces and writes the 2 outputs.

#define NCLS 85     // C + 5 with C = 80
#define CVAL 80
#define BLK  256
#define APT  4      // anchors per thread

__device__ __forceinline__ float sigm(float x) {
    return 1.0f / (1.0f + expf(-x));
}

__global__ void __launch_bounds__(BLK)
yolo_fused_kernel(const float* __restrict__ pred,
                  const float* __restrict__ ann,
                  const float* __restrict__ anc,
                  float* __restrict__ partial,   // (B, P, 3)
                  float* __restrict__ out,
                  int A, int M, int B, int P)
{
    const int b   = blockIdx.y;
    const int tid = threadIdx.x;

    // ---- stage this image's boxes in LDS (M <= 64; here 32) ----
    __shared__ float4 s_cor[64];   // x1, y1, x2, y2 (inf-killed if invalid)
    __shared__ float4 s_ctr[64];   // cx, cy, w, h
    __shared__ float  s_area[64];
    __shared__ int    s_cls[64];

    if (tid < (unsigned)M) {
        const int m = tid;
        const float* r = ann + ((long long)b * M + m) * 5;
        const float x = r[0], y = r[1], w = r[2], h = r[3], c = r[4];
        const float cx = x + 0.5f * w;      // top-left -> center (ref fp order)
        const float cy = y + 0.5f * h;
        const bool valid = (c != -1.0f);
        if (valid) {
            s_cor[m] = make_float4(cx - 0.5f * w, cy - 0.5f * h,
                                   cx + 0.5f * w, cy + 0.5f * h);
            s_area[m] = w * h;
        } else {
            // +inf corners force iw clamp to 0 -> iou = 0 (< 0.5, never a
            // positive match; argmax winner irrelevant below threshold).
            const float inf = INFINITY;
            s_cor[m] = make_float4(inf, inf, inf, inf);
            s_area[m] = 0.0f;
        }
        s_ctr[m] = make_float4(cx, cy, w, h);
        s_cls[m] = valid ? (int)c : 0;
    }
    __syncthreads();

    float cls_sum = 0.0f, reg_sq = 0.0f, np = 0.0f;

    for (int k = 0; k < APT; ++k) {
        const int a = blockIdx.x * (BLK * APT) + k * BLK + tid;
        if (a >= A) break;

        const float4 av = ((const float4*)anc)[a];
        const float acx = av.x, acy = av.y, aw = av.z, ah = av.w;
        const float ax1 = acx - 0.5f * aw, ay1 = acy - 0.5f * ah;
        const float ax2 = acx + 0.5f * aw, ay2 = acy + 0.5f * ah;
        const float aarea = aw * ah;

        // IoU max / argmax (first index wins ties, matching jnp.argmax)
        float best = -INFINITY;
        int bm = 0;
        #pragma unroll 4
        for (int m = 0; m < M; ++m) {
            const float4 bc = s_cor[m];         // broadcast ds_read_b128
            float iw = fminf(ax2, bc.z) - fmaxf(ax1, bc.x);
            float ih = fminf(ay2, bc.w) - fmaxf(ay1, bc.y);
            iw = fmaxf(iw, 0.0f);
            ih = fmaxf(ih, 0.0f);
            const float inter = iw * ih;
            const float iou = inter / (aarea + s_area[m] - inter);
            if (iou > best) { best = iou; bm = m; }
        }

        if (best >= 0.5f) {      // positive anchor
            np += 1.0f;
            const float4 bx = s_ctr[bm];
            const int kc = s_cls[bm];

            const float* row = pred + ((long long)b * A + a) * NCLS;
            const float r0 = row[0], r1 = row[1], r2 = row[2], r3 = row[3], r4 = row[4];
            const float e0 = sigm(r0) - sigm(bx.x - acx);
            const float e1 = sigm(r1) - sigm(bx.y - acy);
            const float e2 = r2 - logf(fmaxf(bx.z, 1.0f) / aw);
            const float e3 = r3 - logf(fmaxf(bx.w, 1.0f) / ah);
            const float e4 = r4 - 1.0f;
            reg_sq += e0*e0 + e1*e1 + e2*e2 + e3*e3 + e4*e4;

            for (int c = 0; c < CVAL; ++c) {
                const float p = row[5 + c];
                cls_sum += (c == kc) ? -logf(p) : -logf(1.0f - p);
            }
        }
    }

    // ---- block reduction: 64-wide shuffle, then LDS across the 4 waves ----
    for (int off = 32; off > 0; off >>= 1) {
        cls_sum += __shfl_down(cls_sum, off);
        reg_sq  += __shfl_down(reg_sq,  off);
        np      += __shfl_down(np,      off);
    }
    __shared__ float s_red[4][3];
    const int wave = tid >> 6;
    const int lane = tid & 63;
    if (lane == 0) {
        s_red[wave][0] = cls_sum;
        s_red[wave][1] = reg_sq;
        s_red[wave][2] = np;
    }
    __syncthreads();
    if (tid == 0) {
        float c = 0.0f, r = 0.0f, n = 0.0f;
        for (int w = 0; w < 4; ++w) { c += s_red[w][0]; r += s_red[w][1]; n += s_red[w][2]; }
        float* dst = partial + ((long long)b * P + blockIdx.x) * 3;
        dst[0] = c; dst[1] = r; dst[2] = n;
    }

    // ---- grid-wide sync, then block (0,0) finalizes ----
    cg::this_grid().sync();

    if (blockIdx.x == 0 && blockIdx.y == 0) {
        const int bi = tid >> 4;       // image (0..15)
        const int j  = tid & 15;       // lane within image group
        float c = 0.0f, r = 0.0f, n = 0.0f;
        if (bi < B) {
            for (int p = j; p < P; p += 16) {
                const float* s = partial + ((long long)bi * P + p) * 3;
                c += s[0]; r += s[1]; n += s[2];
            }
        }
        for (int m = 8; m > 0; m >>= 1) {   // reduce 16-lane group
            c += __shfl_xor(c, m);
            r += __shfl_xor(r, m);
            n += __shfl_xor(n, m);
        }
        __shared__ float f_c[16], f_r[16];
        if (j == 0 && bi < B) {
            const float denom = fmaxf(n, 1.0f);
            f_c[bi] = c / denom;                                  // cls: sum/denom
            f_r[bi] = (n > 0.0f) ? r / (denom * denom) : 0.0f;    // reg: sum/denom^2
        }
        __syncthreads();
        if (tid == 0) {
            float cs = 0.0f, rs = 0.0f;
            for (int i = 0; i < B; ++i) { cs += f_c[i]; rs += f_r[i]; }
            out[0] = cs / (float)B;
            out[1] = rs / (float)B;
        }
    }
}

extern "C" void kernel_launch(void* const* d_in, const int* in_sizes, int n_in,
                              void* d_out, int out_size, void* d_ws, size_t ws_size,
                              hipStream_t stream) {
    const float* pred = (const float*)d_in[0];
    const float* ann  = (const float*)d_in[1];
    const float* anc  = (const float*)d_in[2];
    float* out = (float*)d_out;

    int A = in_sizes[2] / 4;                    // 17328
    int B = in_sizes[0] / (A * NCLS);           // 16
    int M = in_sizes[1] / (5 * B);              // 32
    int P = (A + BLK * APT - 1) / (BLK * APT);  // 17 blocks per image

    float* partial = (float*)d_ws;              // (B, P, 3)

    void* args[] = { (void*)&pred, (void*)&ann, (void*)&anc, (void*)&partial,
                     (void*)&out, (void*)&A, (void*)&M, (void*)&B, (void*)&P };
    hipLaunchCooperativeKernel((const void*)yolo_fused_kernel,
                               dim3(P, B), dim3(BLK), args, 0, stream);
}

// Round 4
// 158.884 us; speedup vs baseline: 1.2408x; 1.2408x over previous
//
#include <hip/hip_runtime.h>
#include <math.h>

// YOLOv3 loss on MI355X — two plain dispatches (cooperative launch costs
// ~50 us/replay under graph capture on this harness; see R3 post-mortem).
// Layouts: pred (B, A, 85) f32 [0..4 reg, 5..84 cls probs]; ann (B, M, 5) f32
// [x_tl, y_tl, w, h, cls(-1=pad)]; anchors (A, 4) f32 [cx, cy, w, h].
// d_ws: per-block partials [B][P][3] = {cls_sum, reg_sq_sum, npos}, written
// unconditionally by kernel 1 -> no zero-init dispatch needed.

#define NCLS 85     // C + 5 with C = 80
#define CVAL 80
#define BLK  256
#define APT  4      // anchors per thread -> P = 17 blocks/image

__device__ __forceinline__ float sigm(float x) {
    return 1.0f / (1.0f + expf(-x));
}

__global__ void __launch_bounds__(BLK)
yolo_match_kernel(const float* __restrict__ pred,
                  const float* __restrict__ ann,
                  const float* __restrict__ anc,
                  float* __restrict__ partial,   // (B, P, 3)
                  int A, int M, int P)
{
    const int b   = blockIdx.y;
    const int tid = threadIdx.x;

    // ---- stage this image's boxes in LDS (M <= 64; here 32) ----
    __shared__ float4 s_cor[64];   // x1, y1, x2, y2 (+inf-killed if invalid)
    __shared__ float4 s_ctr[64];   // cx, cy, w, h
    __shared__ float  s_area[64];
    __shared__ int    s_cls[64];

    if (tid < (unsigned)M) {
        const int m = tid;
        const float* r = ann + ((long long)b * M + m) * 5;
        const float x = r[0], y = r[1], w = r[2], h = r[3], c = r[4];
        const float cx = x + 0.5f * w;      // top-left -> center (ref fp order)
        const float cy = y + 0.5f * h;
        const bool valid = (c != -1.0f);
        if (valid) {
            s_cor[m] = make_float4(cx - 0.5f * w, cy - 0.5f * h,
                                   cx + 0.5f * w, cy + 0.5f * h);
            s_area[m] = w * h;
        } else {
            // +inf corners -> iw clamps to 0 -> iou = 0 (< 0.5): the padded
            // box can never make an anchor positive, and bm is only consumed
            // when best >= 0.5, so the argmax winner below threshold is moot.
            const float inf = INFINITY;
            s_cor[m] = make_float4(inf, inf, inf, inf);
            s_area[m] = 0.0f;
        }
        s_ctr[m] = make_float4(cx, cy, w, h);
        s_cls[m] = valid ? (int)c : 0;
    }
    __syncthreads();

    float cls_sum = 0.0f, reg_sq = 0.0f, np = 0.0f;

    for (int k = 0; k < APT; ++k) {
        const int a = blockIdx.x * (BLK * APT) + k * BLK + tid;
        if (a >= A) break;

        const float4 av = ((const float4*)anc)[a];
        const float acx = av.x, acy = av.y, aw = av.z, ah = av.w;
        const float ax1 = acx - 0.5f * aw, ay1 = acy - 0.5f * ah;
        const float ax2 = acx + 0.5f * aw, ay2 = acy + 0.5f * ah;
        const float aarea = aw * ah;

        // IoU max / argmax (first index wins ties, matching jnp.argmax)
        float best = -INFINITY;
        int bm = 0;
        #pragma unroll 4
        for (int m = 0; m < M; ++m) {
            const float4 bc = s_cor[m];         // broadcast ds_read_b128
            float iw = fminf(ax2, bc.z) - fmaxf(ax1, bc.x);
            float ih = fminf(ay2, bc.w) - fmaxf(ay1, bc.y);
            iw = fmaxf(iw, 0.0f);
            ih = fmaxf(ih, 0.0f);
            const float inter = iw * ih;
            const float iou = inter / (aarea + s_area[m] - inter);
            if (iou > best) { best = iou; bm = m; }
        }

        if (best >= 0.5f) {      // positive anchor: contributes to both losses
            np += 1.0f;
            const float4 bx = s_ctr[bm];
            const int kc = s_cls[bm];

            const float* row = pred + ((long long)b * A + a) * NCLS;
            const float r0 = row[0], r1 = row[1], r2 = row[2], r3 = row[3], r4 = row[4];
            const float e0 = sigm(r0) - sigm(bx.x - acx);
            const float e1 = sigm(r1) - sigm(bx.y - acy);
            const float e2 = r2 - logf(fmaxf(bx.z, 1.0f) / aw);
            const float e3 = r3 - logf(fmaxf(bx.w, 1.0f) / ah);
            const float e4 = r4 - 1.0f;
            reg_sq += e0*e0 + e1*e1 + e2*e2 + e3*e3 + e4*e4;

            for (int c = 0; c < CVAL; ++c) {
                const float p = row[5 + c];
                cls_sum += (c == kc) ? -logf(p) : -logf(1.0f - p);
            }
        }
    }

    // ---- block reduction: 64-wide shuffle, then LDS across the 4 waves ----
    for (int off = 32; off > 0; off >>= 1) {
        cls_sum += __shfl_down(cls_sum, off);
        reg_sq  += __shfl_down(reg_sq,  off);
        np      += __shfl_down(np,      off);
    }
    __shared__ float s_red[4][3];
    const int wave = tid >> 6;
    const int lane = tid & 63;
    if (lane == 0) {
        s_red[wave][0] = cls_sum;
        s_red[wave][1] = reg_sq;
        s_red[wave][2] = np;
    }
    __syncthreads();
    if (tid == 0) {
        float c = 0.0f, r = 0.0f, n = 0.0f;
        for (int w = 0; w < 4; ++w) { c += s_red[w][0]; r += s_red[w][1]; n += s_red[w][2]; }
        float* dst = partial + ((long long)b * P + blockIdx.x) * 3;
        dst[0] = c; dst[1] = r; dst[2] = n;
    }
}

// One wave: 4 lanes per image reduce the P=17 partials, then lane 0 combines.
__global__ void __launch_bounds__(64)
yolo_finalize_kernel(const float* __restrict__ partial,
                     float* __restrict__ out, int B, int P)
{
    const int t = threadIdx.x;
    const int b = t >> 2;        // image (0..15)
    const int j = t & 3;         // lane within image group
    float c = 0.0f, r = 0.0f, n = 0.0f;
    if (b < B) {
        for (int p = j; p < P; p += 4) {
            const float* s = partial + ((long long)b * P + p) * 3;
            c += s[0]; r += s[1]; n += s[2];
        }
    }
    for (int m = 2; m > 0; m >>= 1) {   // reduce 4-lane group
        c += __shfl_xor(c, m);
        r += __shfl_xor(r, m);
        n += __shfl_xor(n, m);
    }
    __shared__ float s_c[16], s_r[16];
    if (j == 0 && b < B) {
        const float denom = fmaxf(n, 1.0f);
        s_c[b] = c / denom;                                   // cls: sum/denom
        s_r[b] = (n > 0.0f) ? r / (denom * denom) : 0.0f;     // reg: sum/denom^2
    }
    __syncthreads();
    if (t == 0) {
        float cs = 0.0f, rs = 0.0f;
        for (int i = 0; i < B; ++i) { cs += s_c[i]; rs += s_r[i]; }
        out[0] = cs / (float)B;
        out[1] = rs / (float)B;
    }
}

extern "C" void kernel_launch(void* const* d_in, const int* in_sizes, int n_in,
                              void* d_out, int out_size, void* d_ws, size_t ws_size,
                              hipStream_t stream) {
    const float* pred = (const float*)d_in[0];
    const float* ann  = (const float*)d_in[1];
    const float* anc  = (const float*)d_in[2];
    float* out = (float*)d_out;

    const int A = in_sizes[2] / 4;                     // 17328
    const int B = in_sizes[0] / (A * NCLS);            // 16
    const int M = in_sizes[1] / (5 * B);               // 32
    const int P = (A + BLK * APT - 1) / (BLK * APT);   // 17 blocks per image

    float* partial = (float*)d_ws;                     // (B, P, 3)

    yolo_match_kernel<<<dim3(P, B), dim3(BLK), 0, stream>>>(pred, ann, anc,
                                                            partial, A, M, P);
    yolo_finalize_kernel<<<1, 64, 0, stream>>>(partial, out, B, P);
}

// Round 5
// 145.590 us; speedup vs baseline: 1.3541x; 1.0913x over previous
//
#include <hip/hip_runtime.h>
#include <math.h>

// YOLOv3 loss on MI355X — R2 configuration (best measured: 146.6 us).
// Timed window is dominated by harness-fixed work: 368 MB d_ws re-poison fill
// (~56 us @ 84% HBM peak) + pristine-input restore copy (~56 us); our two
// dispatches are <6 us combined and never appear in rocprof top-5. Cooperative
// launch costs ~50 us/replay here (R3); APT/float4-LDS variants are within
// the +/-6 us harness noise band (R4). Keep the simple 2-dispatch structure.
//
// Layouts: pred (B, A, 85) f32 [0..4 reg, 5..84 cls probs]; ann (B, M, 5) f32
// [x_tl, y_tl, w, h, cls(-1=pad)]; anchors (A, 4) f32 [cx, cy, w, h].
// d_ws: per-block partials [B][P][3] = {cls_sum, reg_sq_sum, npos}; every slot
// written unconditionally by kernel 1 -> no zero-init dispatch needed.

#define NCLS 85   // C + 5 with C = 80
#define CVAL 80
#define BLK  256

__device__ __forceinline__ float sigm(float x) {
    return 1.0f / (1.0f + expf(-x));
}

__global__ void __launch_bounds__(BLK)
yolo_match_kernel(const float* __restrict__ pred,
                  const float* __restrict__ ann,
                  const float* __restrict__ anc,
                  float* __restrict__ partial,   // (B, P, 3)
                  int A, int M)
{
    const int b = blockIdx.y;
    const int a = blockIdx.x * BLK + threadIdx.x;

    // Stage boxes for this image in LDS (M <= 64; here M = 32).
    __shared__ float s_bx1[64], s_by1[64], s_bx2[64], s_by2[64];
    __shared__ float s_bcx[64], s_bcy[64], s_bw[64], s_bh[64], s_area[64];
    __shared__ int   s_cls[64];

    if (threadIdx.x < (unsigned)M) {
        const int m = threadIdx.x;
        const float* r = ann + ((long long)b * M + m) * 5;
        const float x = r[0], y = r[1], w = r[2], h = r[3], c = r[4];
        const float cx = x + 0.5f * w;     // top-left -> center (ref fp order)
        const float cy = y + 0.5f * h;
        s_bcx[m] = cx; s_bcy[m] = cy; s_bw[m] = w; s_bh[m] = h;
        s_bx1[m] = cx - 0.5f * w; s_by1[m] = cy - 0.5f * h;
        s_bx2[m] = cx + 0.5f * w; s_by2[m] = cy + 0.5f * h;
        s_area[m] = w * h;
        s_cls[m] = (c != -1.0f) ? (int)c : -1;
    }
    __syncthreads();

    float cls_sum = 0.0f, reg_sq = 0.0f, np = 0.0f;

    if (a < A) {
        const float4 av = ((const float4*)anc)[a];
        const float acx = av.x, acy = av.y, aw = av.z, ah = av.w;
        const float ax1 = acx - 0.5f * aw, ay1 = acy - 0.5f * ah;
        const float ax2 = acx + 0.5f * aw, ay2 = acy + 0.5f * ah;
        const float aarea = aw * ah;

        // IoU max / argmax (first index wins ties, matching jnp.argmax).
        float best = -INFINITY;
        int bm = 0;
        for (int m = 0; m < M; ++m) {
            float iw = fminf(ax2, s_bx2[m]) - fmaxf(ax1, s_bx1[m]);
            float ih = fminf(ay2, s_by2[m]) - fmaxf(ay1, s_by1[m]);
            iw = fmaxf(iw, 0.0f);
            ih = fmaxf(ih, 0.0f);
            const float inter = iw * ih;
            float iou = inter / (aarea + s_area[m] - inter);
            if (s_cls[m] < 0) iou = -INFINITY;   // padded boxes never win
            if (iou > best) { best = iou; bm = m; }
        }

        if (best >= 0.5f) {   // positive anchor: contributes to both losses
            np = 1.0f;
            const float bcx = s_bcx[bm], bcy = s_bcy[bm];
            const float bw = s_bw[bm], bh = s_bh[bm];
            const int k = s_cls[bm];

            const float* row = pred + ((long long)b * A + a) * NCLS;

            const float r0 = row[0], r1 = row[1], r2 = row[2], r3 = row[3], r4 = row[4];
            const float e0 = sigm(r0) - sigm(bcx - acx);
            const float e1 = sigm(r1) - sigm(bcy - acy);
            const float e2 = r2 - logf(fmaxf(bw, 1.0f) / aw);
            const float e3 = r3 - logf(fmaxf(bh, 1.0f) / ah);
            const float e4 = r4 - 1.0f;
            reg_sq = e0*e0 + e1*e1 + e2*e2 + e3*e3 + e4*e4;

            for (int c = 0; c < CVAL; ++c) {
                const float p = row[5 + c];
                cls_sum += (c == k) ? -logf(p) : -logf(1.0f - p);
            }
        }
    }

    // Block reduction: wave shuffle (64-wide) then LDS across the 4 waves.
    for (int off = 32; off > 0; off >>= 1) {
        cls_sum += __shfl_down(cls_sum, off);
        reg_sq  += __shfl_down(reg_sq,  off);
        np      += __shfl_down(np,      off);
    }
    __shared__ float s_red[4][3];
    const int wave = threadIdx.x >> 6;
    const int lane = threadIdx.x & 63;
    if (lane == 0) {
        s_red[wave][0] = cls_sum;
        s_red[wave][1] = reg_sq;
        s_red[wave][2] = np;
    }
    __syncthreads();
    if (threadIdx.x == 0) {
        float c = 0.0f, r = 0.0f, n = 0.0f;
        for (int w = 0; w < 4; ++w) { c += s_red[w][0]; r += s_red[w][1]; n += s_red[w][2]; }
        float* dst = partial + ((long long)b * gridDim.x + blockIdx.x) * 3;
        dst[0] = c; dst[1] = r; dst[2] = n;
    }
}

// One block of 256 threads: 16 threads per image reduce the P partials,
// then thread 0 combines the B per-image losses.
__global__ void __launch_bounds__(256)
yolo_finalize_kernel(const float* __restrict__ partial,
                     float* __restrict__ out, int B, int P)
{
    const int t = threadIdx.x;
    const int b = t >> 4;        // image (0..15)
    const int j = t & 15;        // lane within image group
    float c = 0.0f, r = 0.0f, n = 0.0f;
    if (b < B) {
        for (int p = j; p < P; p += 16) {
            const float* s = partial + ((long long)b * P + p) * 3;
            c += s[0]; r += s[1]; n += s[2];
        }
    }
    // reduce within the 16-lane group (aligned inside a 64-wide wave)
    for (int m = 8; m > 0; m >>= 1) {
        c += __shfl_xor(c, m);
        r += __shfl_xor(r, m);
        n += __shfl_xor(n, m);
    }
    __shared__ float s_c[16], s_r[16];
    if (j == 0 && b < B) {
        const float denom = fmaxf(n, 1.0f);
        s_c[b] = c / denom;                                   // cls: sum/denom
        s_r[b] = (n > 0.0f) ? r / (denom * denom) : 0.0f;     // reg: sum/denom^2
    }
    __syncthreads();
    if (t == 0) {
        float cs = 0.0f, rs = 0.0f;
        for (int i = 0; i < B; ++i) { cs += s_c[i]; rs += s_r[i]; }
        out[0] = cs / (float)B;
        out[1] = rs / (float)B;
    }
}

extern "C" void kernel_launch(void* const* d_in, const int* in_sizes, int n_in,
                              void* d_out, int out_size, void* d_ws, size_t ws_size,
                              hipStream_t stream) {
    const float* pred = (const float*)d_in[0];
    const float* ann  = (const float*)d_in[1];
    const float* anc  = (const float*)d_in[2];
    float* out = (float*)d_out;

    const int A = in_sizes[2] / 4;                  // 17328
    const int B = in_sizes[0] / (A * NCLS);         // 16
    const int M = in_sizes[1] / (5 * B);            // 32
    const int P = (A + BLK - 1) / BLK;              // 68 blocks per image

    float* partial = (float*)d_ws;                  // (B, P, 3) floats

    dim3 grid(P, B);
    yolo_match_kernel<<<grid, dim3(BLK), 0, stream>>>(pred, ann, anc, partial, A, M);
    yolo_finalize_kernel<<<1, 256, 0, stream>>>(partial, out, B, P);
}